// Round 7
// baseline (1017.055 us; speedup 1.0000x reference)
//
#include <hip/hip_runtime.h>
#include <cstdint>
#include <cstddef>

// B=8, S=12, N=4096, F=4, H=64
// Stage-1 INT8 (adj fixed-point i8; h,x i8). Key round-7 change: all use-once
// streaming buffers (Cpart, gact, raw inputs, z outputs) use non-temporal
// loads/stores so adj_i8 (16.75 MB) + PB (2 MB) stay L2-resident across the 12
// steps (block flat-id %8 == bx%8 pins each 128-row adj tile to one XCD; 2.1 MB
// adj + 2 MB PB per XCD < 4 MB L2).

typedef unsigned short u16;
typedef short s8v __attribute__((ext_vector_type(8)));   // 8 x bf16 bits
typedef float f4v __attribute__((ext_vector_type(4)));   // fp32 MFMA acc
typedef int   i4v __attribute__((ext_vector_type(4)));   // i8 MFMA operands/acc
typedef unsigned int u4v __attribute__((ext_vector_type(4)));

__device__ __forceinline__ u16 f2bf(float x){
  union { float f; uint32_t u; } v; v.f = x;
  uint32_t r = v.u + 0x7FFFu + ((v.u >> 16) & 1u);   // RNE
  return (u16)(r >> 16);
}
__device__ __forceinline__ float bf2f(u16 x){
  union { uint32_t u; float f; } v; v.u = ((uint32_t)x) << 16; return v.f;
}
__device__ __forceinline__ float frcp(float x){ return __builtin_amdgcn_rcpf(x); }
__device__ __forceinline__ float fsig(float x){ return frcp(1.0f + __expf(-x)); }
__device__ __forceinline__ float ftanh(float x){ return 1.0f - 2.0f * frcp(1.0f + __expf(2.0f * x)); }
__device__ __forceinline__ int8_t f2i8(float x){
  int v = (int)rintf(x);
  v = v > 127 ? 127 : (v < -127 ? -127 : v);
  return (int8_t)v;
}
// non-temporal helpers (evict-first in L2 — keep adj/PB resident)
__device__ __forceinline__ u4v ntld4(const void* p){ return __builtin_nontemporal_load((const u4v*)p); }
__device__ __forceinline__ void ntst4(void* p, u4v v){ __builtin_nontemporal_store(v, (u4v*)p); }
__device__ __forceinline__ u16 ntldh(const u16* p){ return __builtin_nontemporal_load(p); }
__device__ __forceinline__ void ntsth(u16* p, u16 v){ __builtin_nontemporal_store(v, p); }
__device__ __forceinline__ float ntldf(const float* p){ return __builtin_nontemporal_load(p); }
__device__ __forceinline__ void ntstf(float* p, float v){ __builtin_nontemporal_store(v, p); }

typedef const __attribute__((address_space(1))) unsigned int* gp_t;
typedef __attribute__((address_space(3))) unsigned int* lp_t;
__device__ __forceinline__ void glds16(const void* g, void* l){
  __builtin_amdgcn_global_load_lds((gp_t)g, (lp_t)l, 16, 0, 0);
}

// ---------------- Stage-1 INT8: 128x128 tile, BK=64, split-K ----------------
__global__ __launch_bounds__(256)
void gemm_s1_i8(const int8_t* __restrict__ A, const int8_t* __restrict__ Bt,
                u16* __restrict__ Cpart, int Ncols, int ksl, float cscale)
{
  __shared__ int8_t As[128*64];
  __shared__ int8_t Bs[128*64];
  const int t  = threadIdx.x;
  const int l  = t & 63;
  const int w  = t >> 6;
  const int wm = (w >> 1) * 64;
  const int wc = (w & 1) * 64;
  const int mb = blockIdx.x * 128;
  const int nb = blockIdx.y * 128;
  const int k0 = blockIdx.z * ksl;

  i4v acc[4][4];
  #pragma unroll
  for (int i = 0; i < 4; ++i)
    #pragma unroll
    for (int j = 0; j < 4; ++j) acc[i][j] = (i4v)0;

  const int r1 = t >> 2;
  const int g1 = ((t & 3) ^ ((r1 >> 1) & 3)) * 16;
  const int8_t* a1 = A  + (size_t)(mb + r1)      * 4096 + k0 + g1;
  const int8_t* a2 = A  + (size_t)(mb + r1 + 64) * 4096 + k0 + g1;
  const int8_t* b1 = Bt + (size_t)(nb + r1)      * 4096 + k0 + g1;
  const int8_t* b2 = Bt + (size_t)(nb + r1 + 64) * 4096 + k0 + g1;

  const int kpos = ((l >> 4) ^ ((l >> 1) & 3)) * 16;
  const int rA = l & 15;

  for (int kk = 0; kk < ksl; kk += 64) {
    glds16(a1 + kk, As + (size_t)t * 16);
    glds16(a2 + kk, As + (size_t)(t + 256) * 16);
    glds16(b1 + kk, Bs + (size_t)t * 16);
    glds16(b2 + kk, Bs + (size_t)(t + 256) * 16);
    __syncthreads();
    i4v af[4], bf[4];
    #pragma unroll
    for (int mt = 0; mt < 4; ++mt)
      af[mt] = *(const i4v*)&As[(wm + mt * 16 + rA) * 64 + kpos];
    #pragma unroll
    for (int nt = 0; nt < 4; ++nt)
      bf[nt] = *(const i4v*)&Bs[(wc + nt * 16 + rA) * 64 + kpos];
    #pragma unroll
    for (int mt = 0; mt < 4; ++mt)
      #pragma unroll
      for (int nt = 0; nt < 4; ++nt)
        acc[mt][nt] = __builtin_amdgcn_mfma_i32_16x16x64_i8(af[mt], bf[nt], acc[mt][nt], 0, 0, 0);
    __syncthreads();
  }

  u16* Cs = Cpart + (size_t)blockIdx.z * 4096 * Ncols;
  const int colo = l & 15;
  const int rowo = (l >> 4) * 4;
  #pragma unroll
  for (int mt = 0; mt < 4; ++mt)
    #pragma unroll
    for (int nt = 0; nt < 4; ++nt)
      #pragma unroll
      for (int r = 0; r < 4; ++r) {
        int gr = mb + wm + mt * 16 + rowo + r;
        int gc = nb + wc + nt * 16 + colo;
        ntsth(&Cs[(size_t)gr * Ncols + gc], f2bf((float)acc[mt][nt][r] * cscale));
      }
}

// O[i] = sum_{z<4} P[z*SL + i]  (bf16) — used once for the AX hoist
__global__ __launch_bounds__(256)
void reduceN(const u16* __restrict__ P, u16* __restrict__ O, size_t SL)
{
  size_t i = ((size_t)blockIdx.x * 256 + threadIdx.x) * 8;
  if (i >= SL) return;
  float s[8] = {0,0,0,0,0,0,0,0};
  #pragma unroll
  for (int z = 0; z < 4; ++z) {
    u4v v = ntld4(P + z * SL + i);
    #pragma unroll
    for (int q = 0; q < 4; ++q) {
      union { uint32_t u; float f; } lo, hi;
      lo.u = v[q] << 16; hi.u = v[q] & 0xFFFF0000u;
      s[2*q] += lo.f; s[2*q+1] += hi.f;
    }
  }
  uint4 o; uint32_t* ow = (uint32_t*)&o;
  #pragma unroll
  for (int q = 0; q < 4; ++q)
    ow[q] = (uint32_t)f2bf(s[2*q]) | ((uint32_t)f2bf(s[2*q+1]) << 16);
  *(uint4*)(O + i) = o;   // AXb is re-read every step: keep cached
}

// ---------- Stage-2 fused: (sum 4 AH slices | AX x-cols | pad) @ WT^T, then
// bias + sigmoid (cols<192) / tanh (cols>=192) -> gact bf16 ----------
__global__ __launch_bounds__(256)
void gemm_s2(const u16* __restrict__ AH, const u16* __restrict__ AXb,
             const u16* __restrict__ WT, const float* __restrict__ b1v,
             const float* __restrict__ b2v, u16* __restrict__ gact, int tstep)
{
  __shared__ u16 As[64*104];
  __shared__ u16 Bs[64*104];
  const int t = threadIdx.x;
  const int l = t & 63, w = t >> 6;
  const int wm = (w >> 1) * 32, wc = (w & 1) * 32;
  const int mb = blockIdx.x * 64, nb = blockIdx.y * 64;
  const size_t SL = 32768ull * 64;

  #pragma unroll
  for (int pass = 0; pass < 2; ++pass) {
    int idx = t + pass * 256;
    int row = idx >> 3, oct = idx & 7;
    size_t base = (size_t)(mb + row) * 64 + oct * 8;
    float s[8] = {0,0,0,0,0,0,0,0};
    #pragma unroll
    for (int z = 0; z < 4; ++z) {
      u4v v = ntld4(AH + z * SL + base);
      #pragma unroll
      for (int q = 0; q < 4; ++q) {
        union { uint32_t u; float f; } lo, hi;
        lo.u = v[q] << 16; hi.u = v[q] & 0xFFFF0000u;
        s[2*q] += lo.f; s[2*q+1] += hi.f;
      }
    }
    uint4 o; uint32_t* ow = (uint32_t*)&o;
    #pragma unroll
    for (int q = 0; q < 4; ++q)
      ow[q] = (uint32_t)f2bf(s[2*q]) | ((uint32_t)f2bf(s[2*q+1]) << 16);
    *(uint4*)&As[row * 104 + oct * 8] = o;
  }
  {
    int row = t >> 2, q = t & 3;
    uint4 o = {0, 0, 0, 0};
    if (q == 0) {
      int r = mb + row, n = r >> 3, b = r & 7;
      const uint32_t* src = (const uint32_t*)(AXb + (size_t)n * 384 + tstep * 32 + b * 4);
      o.x = src[0]; o.y = src[1];
    }
    *(uint4*)&As[row * 104 + 64 + q * 8] = o;
  }
  #pragma unroll
  for (int pass = 0; pass < 3; ++pass) {
    int idx = t + pass * 256;
    if (idx < 768) {
      int row = idx / 12, seg = idx - row * 12;
      *(uint4*)&Bs[row * 104 + seg * 8] = *(const uint4*)(WT + (size_t)(nb + row) * 96 + seg * 8);
    }
  }
  __syncthreads();

  f4v acc[2][2];
  #pragma unroll
  for (int i = 0; i < 2; ++i)
    #pragma unroll
    for (int j = 0; j < 2; ++j) acc[i][j] = (f4v)0.0f;
  const int rA = l & 15, kg = (l >> 4) * 8;
  #pragma unroll
  for (int kc = 0; kc < 3; ++kc) {
    s8v af[2], bf[2];
    #pragma unroll
    for (int mt = 0; mt < 2; ++mt)
      af[mt] = *(const s8v*)&As[(wm + mt * 16 + rA) * 104 + kc * 32 + kg];
    #pragma unroll
    for (int nt = 0; nt < 2; ++nt)
      bf[nt] = *(const s8v*)&Bs[(wc + nt * 16 + rA) * 104 + kc * 32 + kg];
    #pragma unroll
    for (int mt = 0; mt < 2; ++mt)
      #pragma unroll
      for (int nt = 0; nt < 2; ++nt)
        acc[mt][nt] = __builtin_amdgcn_mfma_f32_16x16x32_bf16(af[mt], bf[nt], acc[mt][nt], 0, 0, 0);
  }

  const int colo = l & 15, rowo = (l >> 4) * 4;
  #pragma unroll
  for (int mt = 0; mt < 2; ++mt)
    #pragma unroll
    for (int nt = 0; nt < 2; ++nt) {
      int gc = nb + wc + nt * 16 + colo;
      float bb = (gc < 192) ? b1v[gc] : b2v[gc - 192];
      #pragma unroll
      for (int r = 0; r < 4; ++r) {
        int gr = mb + wm + mt * 16 + rowo + r;
        float v = acc[mt][nt][r] + bb;
        float a = (gc < 192) ? fsig(v) : ftanh(v);
        ntsth(&gact[(size_t)gr * 256 + gc], f2bf(a));
      }
    }
}

// adj fp32 -> i8 fixed-point: round(adj * 127*2048), adj in [0, 2/4096)
__global__ void conv_adj_i8(const float* __restrict__ adj, int8_t* __restrict__ out){
  size_t i = ((size_t)blockIdx.x * 256 + threadIdx.x) * 4;
  u4v v = ntld4(adj + i);
  const float s = 127.0f * 2048.0f;
  union { uint32_t u; float f; } c0, c1, c2, c3;
  c0.u = v[0]; c1.u = v[1]; c2.u = v[2]; c3.u = v[3];
  char4 o;
  o.x = f2i8(c0.f * s); o.y = f2i8(c1.f * s); o.z = f2i8(c2.f * s); o.w = f2i8(c3.f * s);
  *(char4*)(out + i) = o;
}

// WT[j][ch]: ch 0..63 = h-rows (W row 4+ch), 64..67 = x-rows (W row ch-64), 68..95 = 0.
__global__ void build_w(const float* __restrict__ W1, const float* __restrict__ W2,
                        const float* __restrict__ Wih, const float* __restrict__ Whh,
                        const float* __restrict__ D1,
                        u16* __restrict__ WT, u16* __restrict__ WihB,
                        u16* __restrict__ WhhB, u16* __restrict__ D1t){
  int gid = blockIdx.x * 256 + threadIdx.x;
  if (gid < 24576) {
    int j = gid / 96, ch = gid - j * 96;
    float v = 0.0f;
    int rr = (ch < 64) ? (ch + 4) : (ch < 68 ? ch - 64 : -1);
    if (rr >= 0) v = (j < 192) ? W1[(size_t)rr * 192 + j] : W2[(size_t)rr * 64 + (j - 192)];
    WT[gid] = f2bf(v);
  } else if (gid < 40960) {
    int q = gid - 24576; WihB[q] = f2bf(Wih[q]);
  } else if (gid < 57344) {
    int q = gid - 40960; WhhB[q] = f2bf(Whh[q]);
  } else if (gid < 59392) {
    int q = gid - 57344;
    int j = q >> 6, hh = q & 63;
    D1t[q] = f2bf(D1[(size_t)hh * 32 + j]);
  }
}

// PB rows r = b*64+hh (512), init from struc_emb at scale 25.4 (i8)
__global__ void init_pb(const float* __restrict__ struc, int8_t* __restrict__ PB){
  int gid = blockIdx.x * 256 + threadIdx.x;      // 512*4096
  int n = gid & 4095;
  int r = gid >> 12;
  int hh = r & 63;
  PB[(size_t)r * 4096 + n] = f2i8(struc[(size_t)n * 64 + hh] * 25.4f);
}

// Xp[col][n] i8 at scale 25.4, col = t*32 + b*4 + f  (384 rows)
__global__ void pack_xall(const float* __restrict__ X, int8_t* __restrict__ Xp){
  int gid = blockIdx.x * 256 + threadIdx.x;      // 384*4096
  int n = gid & 4095;
  int col = gid >> 12;
  int ts = col >> 5, r = col & 31, b = r >> 2, f = r & 3;
  Xp[(size_t)col * 4096 + n] = f2i8(ntldf(&X[(((size_t)(b * 12 + ts)) * 4096 + n) * 4 + f]) * 25.4f);
}

// gact[r=(n*8+b)][j]: j<192 activated gates, 192..255 tanh(conv).
__global__ __launch_bounds__(256)
void enc_update(const u16* __restrict__ gact, const float* __restrict__ struc,
                int8_t* __restrict__ PB, float* __restrict__ zout,
                u16* __restrict__ zbf, int last)
{
  int gid = blockIdx.x * 256 + threadIdx.x;      // 8 * 262144
  int b = gid >> 18;
  int k = gid & 262143;
  int n = k >> 6, hh = k & 63;
  int qi = k + 262144, qo = k + 524288;
  int nf = k  / 192, jf = k  - nf * 192;
  int ni = qi / 192, ji = qi - ni * 192;
  int no = qo / 192, jo = qo - no * 192;
  float fg = bf2f(ntldh(&gact[((size_t)nf * 8 + b) * 256 + jf]));
  float ig = bf2f(ntldh(&gact[((size_t)ni * 8 + b) * 256 + ji]));
  float og = bf2f(ntldh(&gact[((size_t)no * 8 + b) * 256 + jo]));
  float tc = bf2f(ntldh(&gact[((size_t)n  * 8 + b) * 256 + 192 + hh]));
  float c  = fg * struc[k] + ig * tc;
  float hv = og * ftanh(c);
  PB[((size_t)(b * 64 + hh)) * 4096 + n] = f2i8(hv * 127.0f);   // |hv|<1
  if (last) {
    ntstf(&zout[(size_t)b * 262144 + k], hv);
    ntsth(&zbf [(size_t)b * 262144 + k], f2bf(hv));
  }
}

// ---------------- Fused decoder (unchanged from round 6) ----------------
__global__ __launch_bounds__(256)
void dec_fused(const u16* __restrict__ zbf, const u16* __restrict__ WihB,
               const u16* __restrict__ WhhB,
               const float* __restrict__ bih, const float* __restrict__ bhh,
               const u16* __restrict__ D1t, const float* __restrict__ bd1,
               const float* __restrict__ D2, const float* __restrict__ bd2,
               float* __restrict__ recon)
{
  __shared__ u16 whl[256 * 72];
  __shared__ u16 hl[64 * 72];
  const int t = threadIdx.x;
  const int l = t & 63;
  const int w = t >> 6;
  const int r0 = blockIdx.x * 64;
  const int rA = l & 15;
  const int kg = (l >> 4) * 8;

  for (int c = t; c < 2048; c += 256) {
    int j = c >> 3, k8 = (c & 7) * 8;
    *(uint4*)&whl[j * 72 + k8] = *(const uint4*)&WhhB[j * 64 + k8];
  }

  f4v xg[16];
  {
    s8v a0 = *(const s8v*)&zbf[(size_t)(r0 + w * 16 + rA) * 64 + kg];
    s8v a1 = *(const s8v*)&zbf[(size_t)(r0 + w * 16 + rA) * 64 + 32 + kg];
    #pragma unroll
    for (int nt = 0; nt < 16; ++nt) {
      s8v b0 = *(const s8v*)&WihB[(nt * 16 + rA) * 64 + kg];
      s8v b1 = *(const s8v*)&WihB[(nt * 16 + rA) * 64 + 32 + kg];
      f4v a = (f4v)0.0f;
      a = __builtin_amdgcn_mfma_f32_16x16x32_bf16(a0, b0, a, 0, 0, 0);
      a = __builtin_amdgcn_mfma_f32_16x16x32_bf16(a1, b1, a, 0, 0, 0);
      float bb = bih[nt * 16 + rA] + bhh[nt * 16 + rA];
      #pragma unroll
      for (int r = 0; r < 4; ++r) xg[nt][r] = a[r] + bb;
    }
  }
  s8v d1f[4];
  #pragma unroll
  for (int nt = 0; nt < 2; ++nt)
    #pragma unroll
    for (int kc = 0; kc < 2; ++kc)
      d1f[nt * 2 + kc] = *(const s8v*)&D1t[(nt * 16 + rA) * 64 + kc * 32 + kg];
  const float bd1x = bd1[rA], bd1y = bd1[16 + rA];
  const float d2x = D2[rA], d2y = D2[16 + rA];
  const float bd2v = bd2[0];

  float cst[16];
  #pragma unroll
  for (int q = 0; q < 16; ++q) cst[q] = 0.0f;
  s8v ha0 = (s8v)0, ha1 = (s8v)0;
  __syncthreads();

  for (int s = 0; s < 12; ++s) {
    f4v acc[16];
    #pragma unroll
    for (int nt = 0; nt < 16; ++nt) acc[nt] = xg[nt];
    if (s > 0) {
      #pragma unroll
      for (int nt = 0; nt < 16; ++nt) {
        s8v b0 = *(const s8v*)&whl[(nt * 16 + rA) * 72 + kg];
        s8v b1 = *(const s8v*)&whl[(nt * 16 + rA) * 72 + 32 + kg];
        acc[nt] = __builtin_amdgcn_mfma_f32_16x16x32_bf16(ha0, b0, acc[nt], 0, 0, 0);
        acc[nt] = __builtin_amdgcn_mfma_f32_16x16x32_bf16(ha1, b1, acc[nt], 0, 0, 0);
      }
    }
    #pragma unroll
    for (int q = 0; q < 4; ++q)
      #pragma unroll
      for (int r = 0; r < 4; ++r) {
        float i_ = fsig (acc[q     ][r]);
        float f_ = fsig (acc[q + 4 ][r]);
        float g_ = ftanh(acc[q + 8 ][r]);
        float o_ = fsig (acc[q + 12][r]);
        float cc = f_ * cst[q * 4 + r] + i_ * g_;
        cst[q * 4 + r] = cc;
        float hv = o_ * ftanh(cc);
        hl[(w * 16 + (l >> 4) * 4 + r) * 72 + q * 16 + rA] = f2bf(hv);
      }
    ha0 = *(const s8v*)&hl[(w * 16 + rA) * 72 + kg];
    ha1 = *(const s8v*)&hl[(w * 16 + rA) * 72 + 32 + kg];
    f4v m0 = (f4v)0.0f, m1 = (f4v)0.0f;
    m0 = __builtin_amdgcn_mfma_f32_16x16x32_bf16(ha0, d1f[0], m0, 0, 0, 0);
    m0 = __builtin_amdgcn_mfma_f32_16x16x32_bf16(ha1, d1f[1], m0, 0, 0, 0);
    m1 = __builtin_amdgcn_mfma_f32_16x16x32_bf16(ha0, d1f[2], m1, 0, 0, 0);
    m1 = __builtin_amdgcn_mfma_f32_16x16x32_bf16(ha1, d1f[3], m1, 0, 0, 0);
    f4v p;
    #pragma unroll
    for (int r = 0; r < 4; ++r)
      p[r] = fmaxf(m0[r] + bd1x, 0.0f) * d2x + fmaxf(m1[r] + bd1y, 0.0f) * d2y;
    #pragma unroll
    for (int mask = 1; mask < 16; mask <<= 1)
      #pragma unroll
      for (int r = 0; r < 4; ++r) p[r] += __shfl_xor(p[r], mask);
    if (rA < 4)
      recon[(size_t)(r0 + w * 16 + (l >> 4) * 4 + rA) * 12 + s] = p[rA] + bd2v;
  }
}

extern "C" void kernel_launch(void* const* d_in, const int* in_sizes, int n_in,
                              void* d_out, int out_size, void* d_ws, size_t ws_size,
                              hipStream_t stream)
{
  (void)in_sizes; (void)n_in; (void)out_size; (void)ws_size;
  const float* X     = (const float*)d_in[0];
  const float* adj   = (const float*)d_in[1];
  const float* struc = (const float*)d_in[2];
  const float* W1    = (const float*)d_in[3];
  const float* b1    = (const float*)d_in[4];
  const float* W2    = (const float*)d_in[5];
  const float* b2    = (const float*)d_in[6];
  const float* Wih   = (const float*)d_in[7];
  const float* Whh   = (const float*)d_in[8];
  const float* bih   = (const float*)d_in[9];
  const float* bhh   = (const float*)d_in[10];
  const float* D1    = (const float*)d_in[11];
  const float* bd1   = (const float*)d_in[12];
  const float* D2    = (const float*)d_in[13];
  const float* bd2   = (const float*)d_in[14];

  char* ws = (char*)d_ws;
  size_t off = 0;
  auto alloc = [&](size_t bytes){ void* p = ws + off; off += (bytes + 255) & ~(size_t)255; return p; };
  int8_t* adj_i8 = (int8_t*)alloc(4096ull * 4096);       // 16.75 MB (L2-resident)
  int8_t* PB     = (int8_t*)alloc(512ull * 4096);        // h cols i8 (L2-resident)
  int8_t* Xp     = (int8_t*)alloc(384ull * 4096);        // x cols i8
  u16*   AXb    = (u16*)  alloc(4096ull * 384 * 2);      // adj@X bf16, all steps
  u16*   Cpart  = (u16*)  alloc(4ull * 4096 * 512 * 2);  // split-K slices (streamed)
  u16*   gact   = (u16*)  alloc(32768ull * 256 * 2);     // activated gates (streamed)
  u16*   zbf    = (u16*)  alloc(32768ull * 64 * 2);
  u16*   WT     = (u16*)  alloc(256ull * 96 * 2);
  u16*   WihB   = (u16*)  alloc(256ull * 64 * 2);
  u16*   WhhB   = (u16*)  alloc(256ull * 64 * 2);
  u16*   D1t    = (u16*)  alloc(32ull * 64 * 2);

  float* zout  = (float*)d_out;                   // [B,N,H]
  float* recon = (float*)d_out + 2097152;         // [B*N, S] flat

  const float cs5 = (float)(2.0 / 4096.0 * 5.0 / (127.0 * 127.0 * 0.1968503937));
  // NOTE: struc/X scale is 25.4 = 127*0.2 -> S_B = 5: cs5 = (2/4096)*(1/2048)... keep explicit:
  const float csX = (float)((2.0 / 4096.0 / 2048.0) * (1.0 / 25.4));  // adj lsb * x lsb
  const float csH = (float)((2.0 / 4096.0 / 2048.0) * (1.0 / 127.0)); // adj lsb * h lsb
  (void)cs5;

  conv_adj_i8<<<16384, 256, 0, stream>>>(adj, adj_i8);
  build_w    <<<  232, 256, 0, stream>>>(W1, W2, Wih, Whh, D1, WT, WihB, WhhB, D1t);
  init_pb    <<< 8192, 256, 0, stream>>>(struc, PB);
  pack_xall  <<< 6144, 256, 0, stream>>>(X, Xp);
  gemm_s1_i8 <<<dim3(32, 3, 4), 256, 0, stream>>>(adj_i8, Xp, Cpart, 384, 1024, csX);
  reduceN    <<<  768, 256, 0, stream>>>(Cpart, AXb, 4096ull * 384);

  for (int t = 0; t < 12; ++t) {
    gemm_s1_i8<<<dim3(32, 4, 4), 256, 0, stream>>>(adj_i8, PB, Cpart, 512, 1024,
                                                   t == 0 ? csX : csH);
    gemm_s2<<<dim3(512, 4), 256, 0, stream>>>(Cpart, AXb, WT, b1, b2, gact, t);
    enc_update<<<8192, 256, 0, stream>>>(gact, struc, PB, zout, zbf, t == 11);
  }

  dec_fused<<<512, 256, 0, stream>>>(zbf, WihB, WhhB, bih, bhh,
                                     D1t, bd1, D2, bd2, recon);
}

// Round 8
// 819.477 us; speedup vs baseline: 1.2411x; 1.2411x over previous
//
#include <hip/hip_runtime.h>
#include <cstdint>
#include <cstddef>

// B=8, S=12, N=4096, F=4, H=64
// Round 8 = round 6 (i8 stage-1, 771 us, absmax 0.0039) + non-temporal hints on
// LOADS ONLY of the use-once streams (Cpart in s2/reduceN, gact in enc_update).
// Stores stay normal (writeback L2). NT-read = evict-first after consumption,
// freeing L2 so adj_i8 (~2.1 MB/XCD, pinned via flat%8==bx%8) + PB survive
// between s1 dispatches. r7's NT-stores (and its 16x-wrong dequant scales)
// reverted.

typedef unsigned short u16;
typedef short s8v __attribute__((ext_vector_type(8)));   // 8 x bf16 bits
typedef float f4v __attribute__((ext_vector_type(4)));   // fp32 MFMA acc
typedef int   i4v __attribute__((ext_vector_type(4)));   // i8 MFMA operands/acc
typedef unsigned int u4v __attribute__((ext_vector_type(4)));

__device__ __forceinline__ u16 f2bf(float x){
  union { float f; uint32_t u; } v; v.f = x;
  uint32_t r = v.u + 0x7FFFu + ((v.u >> 16) & 1u);   // RNE
  return (u16)(r >> 16);
}
__device__ __forceinline__ float bf2f(u16 x){
  union { uint32_t u; float f; } v; v.u = ((uint32_t)x) << 16; return v.f;
}
__device__ __forceinline__ float frcp(float x){ return __builtin_amdgcn_rcpf(x); }
__device__ __forceinline__ float fsig(float x){ return frcp(1.0f + __expf(-x)); }
__device__ __forceinline__ float ftanh(float x){ return 1.0f - 2.0f * frcp(1.0f + __expf(2.0f * x)); }
__device__ __forceinline__ int8_t f2i8(float x){
  int v = (int)rintf(x);
  v = v > 127 ? 127 : (v < -127 ? -127 : v);
  return (int8_t)v;
}
// non-temporal LOAD helpers only (evict-first after read; stores stay normal)
__device__ __forceinline__ u4v ntld4(const void* p){ return __builtin_nontemporal_load((const u4v*)p); }
__device__ __forceinline__ u16 ntldh(const u16* p){ return __builtin_nontemporal_load(p); }

typedef const __attribute__((address_space(1))) unsigned int* gp_t;
typedef __attribute__((address_space(3))) unsigned int* lp_t;
__device__ __forceinline__ void glds16(const void* g, void* l){
  __builtin_amdgcn_global_load_lds((gp_t)g, (lp_t)l, 16, 0, 0);
}

// ---------------- Stage-1 INT8: 128x128 tile, BK=64, split-K ----------------
__global__ __launch_bounds__(256)
void gemm_s1_i8(const int8_t* __restrict__ A, const int8_t* __restrict__ Bt,
                u16* __restrict__ Cpart, int Ncols, int ksl, float cscale)
{
  __shared__ int8_t As[128*64];
  __shared__ int8_t Bs[128*64];
  const int t  = threadIdx.x;
  const int l  = t & 63;
  const int w  = t >> 6;
  const int wm = (w >> 1) * 64;
  const int wc = (w & 1) * 64;
  const int mb = blockIdx.x * 128;
  const int nb = blockIdx.y * 128;
  const int k0 = blockIdx.z * ksl;

  i4v acc[4][4];
  #pragma unroll
  for (int i = 0; i < 4; ++i)
    #pragma unroll
    for (int j = 0; j < 4; ++j) acc[i][j] = (i4v)0;

  const int r1 = t >> 2;
  const int g1 = ((t & 3) ^ ((r1 >> 1) & 3)) * 16;
  const int8_t* a1 = A  + (size_t)(mb + r1)      * 4096 + k0 + g1;
  const int8_t* a2 = A  + (size_t)(mb + r1 + 64) * 4096 + k0 + g1;
  const int8_t* b1 = Bt + (size_t)(nb + r1)      * 4096 + k0 + g1;
  const int8_t* b2 = Bt + (size_t)(nb + r1 + 64) * 4096 + k0 + g1;

  const int kpos = ((l >> 4) ^ ((l >> 1) & 3)) * 16;
  const int rA = l & 15;

  for (int kk = 0; kk < ksl; kk += 64) {
    glds16(a1 + kk, As + (size_t)t * 16);
    glds16(a2 + kk, As + (size_t)(t + 256) * 16);
    glds16(b1 + kk, Bs + (size_t)t * 16);
    glds16(b2 + kk, Bs + (size_t)(t + 256) * 16);
    __syncthreads();
    i4v af[4], bf[4];
    #pragma unroll
    for (int mt = 0; mt < 4; ++mt)
      af[mt] = *(const i4v*)&As[(wm + mt * 16 + rA) * 64 + kpos];
    #pragma unroll
    for (int nt = 0; nt < 4; ++nt)
      bf[nt] = *(const i4v*)&Bs[(wc + nt * 16 + rA) * 64 + kpos];
    #pragma unroll
    for (int mt = 0; mt < 4; ++mt)
      #pragma unroll
      for (int nt = 0; nt < 4; ++nt)
        acc[mt][nt] = __builtin_amdgcn_mfma_i32_16x16x64_i8(af[mt], bf[nt], acc[mt][nt], 0, 0, 0);
    __syncthreads();
  }

  u16* Cs = Cpart + (size_t)blockIdx.z * 4096 * Ncols;
  const int colo = l & 15;
  const int rowo = (l >> 4) * 4;
  #pragma unroll
  for (int mt = 0; mt < 4; ++mt)
    #pragma unroll
    for (int nt = 0; nt < 4; ++nt)
      #pragma unroll
      for (int r = 0; r < 4; ++r) {
        int gr = mb + wm + mt * 16 + rowo + r;
        int gc = nb + wc + nt * 16 + colo;
        Cs[(size_t)gr * Ncols + gc] = f2bf((float)acc[mt][nt][r] * cscale);
      }
}

// O[i] = sum_{z<4} P[z*SL + i]  (bf16) — used once for the AX hoist
__global__ __launch_bounds__(256)
void reduceN(const u16* __restrict__ P, u16* __restrict__ O, size_t SL)
{
  size_t i = ((size_t)blockIdx.x * 256 + threadIdx.x) * 8;
  if (i >= SL) return;
  float s[8] = {0,0,0,0,0,0,0,0};
  #pragma unroll
  for (int z = 0; z < 4; ++z) {
    u4v v = ntld4(P + z * SL + i);
    #pragma unroll
    for (int q = 0; q < 4; ++q) {
      union { uint32_t u; float f; } lo, hi;
      lo.u = v[q] << 16; hi.u = v[q] & 0xFFFF0000u;
      s[2*q] += lo.f; s[2*q+1] += hi.f;
    }
  }
  uint4 o; uint32_t* ow = (uint32_t*)&o;
  #pragma unroll
  for (int q = 0; q < 4; ++q)
    ow[q] = (uint32_t)f2bf(s[2*q]) | ((uint32_t)f2bf(s[2*q+1]) << 16);
  *(uint4*)(O + i) = o;   // AXb re-read every step: normal (cached) store
}

// ---------- Stage-2 fused: (sum 4 AH slices | AX x-cols | pad) @ WT^T, then
// bias + sigmoid (cols<192) / tanh (cols>=192) -> gact bf16 ----------
__global__ __launch_bounds__(256)
void gemm_s2(const u16* __restrict__ AH, const u16* __restrict__ AXb,
             const u16* __restrict__ WT, const float* __restrict__ b1v,
             const float* __restrict__ b2v, u16* __restrict__ gact, int tstep)
{
  __shared__ u16 As[64*104];
  __shared__ u16 Bs[64*104];
  const int t = threadIdx.x;
  const int l = t & 63, w = t >> 6;
  const int wm = (w >> 1) * 32, wc = (w & 1) * 32;
  const int mb = blockIdx.x * 64, nb = blockIdx.y * 64;
  const size_t SL = 32768ull * 64;

  #pragma unroll
  for (int pass = 0; pass < 2; ++pass) {
    int idx = t + pass * 256;
    int row = idx >> 3, oct = idx & 7;
    size_t base = (size_t)(mb + row) * 64 + oct * 8;
    float s[8] = {0,0,0,0,0,0,0,0};
    #pragma unroll
    for (int z = 0; z < 4; ++z) {
      u4v v = ntld4(AH + z * SL + base);   // NT read: evict Cpart after use
      #pragma unroll
      for (int q = 0; q < 4; ++q) {
        union { uint32_t u; float f; } lo, hi;
        lo.u = v[q] << 16; hi.u = v[q] & 0xFFFF0000u;
        s[2*q] += lo.f; s[2*q+1] += hi.f;
      }
    }
    uint4 o; uint32_t* ow = (uint32_t*)&o;
    #pragma unroll
    for (int q = 0; q < 4; ++q)
      ow[q] = (uint32_t)f2bf(s[2*q]) | ((uint32_t)f2bf(s[2*q+1]) << 16);
    *(uint4*)&As[row * 104 + oct * 8] = o;
  }
  {
    int row = t >> 2, q = t & 3;
    uint4 o = {0, 0, 0, 0};
    if (q == 0) {
      int r = mb + row, n = r >> 3, b = r & 7;
      const uint32_t* src = (const uint32_t*)(AXb + (size_t)n * 384 + tstep * 32 + b * 4);
      o.x = src[0]; o.y = src[1];
    }
    *(uint4*)&As[row * 104 + 64 + q * 8] = o;
  }
  #pragma unroll
  for (int pass = 0; pass < 3; ++pass) {
    int idx = t + pass * 256;
    if (idx < 768) {
      int row = idx / 12, seg = idx - row * 12;
      *(uint4*)&Bs[row * 104 + seg * 8] = *(const uint4*)(WT + (size_t)(nb + row) * 96 + seg * 8);
    }
  }
  __syncthreads();

  f4v acc[2][2];
  #pragma unroll
  for (int i = 0; i < 2; ++i)
    #pragma unroll
    for (int j = 0; j < 2; ++j) acc[i][j] = (f4v)0.0f;
  const int rA = l & 15, kg = (l >> 4) * 8;
  #pragma unroll
  for (int kc = 0; kc < 3; ++kc) {
    s8v af[2], bf[2];
    #pragma unroll
    for (int mt = 0; mt < 2; ++mt)
      af[mt] = *(const s8v*)&As[(wm + mt * 16 + rA) * 104 + kc * 32 + kg];
    #pragma unroll
    for (int nt = 0; nt < 2; ++nt)
      bf[nt] = *(const s8v*)&Bs[(wc + nt * 16 + rA) * 104 + kc * 32 + kg];
    #pragma unroll
    for (int mt = 0; mt < 2; ++mt)
      #pragma unroll
      for (int nt = 0; nt < 2; ++nt)
        acc[mt][nt] = __builtin_amdgcn_mfma_f32_16x16x32_bf16(af[mt], bf[nt], acc[mt][nt], 0, 0, 0);
  }

  const int colo = l & 15, rowo = (l >> 4) * 4;
  #pragma unroll
  for (int mt = 0; mt < 2; ++mt)
    #pragma unroll
    for (int nt = 0; nt < 2; ++nt) {
      int gc = nb + wc + nt * 16 + colo;
      float bb = (gc < 192) ? b1v[gc] : b2v[gc - 192];
      #pragma unroll
      for (int r = 0; r < 4; ++r) {
        int gr = mb + wm + mt * 16 + rowo + r;
        float v = acc[mt][nt][r] + bb;
        float a = (gc < 192) ? fsig(v) : ftanh(v);
        gact[(size_t)gr * 256 + gc] = f2bf(a);   // normal store (L2 writeback)
      }
    }
}

// adj fp32 -> i8 fixed-point: round(adj * 127*2048), adj in [0, 2/4096)
__global__ void conv_adj_i8(const float* __restrict__ adj, int8_t* __restrict__ out){
  size_t i = ((size_t)blockIdx.x * 256 + threadIdx.x) * 4;
  float4 v = *(const float4*)(adj + i);
  const float s = 127.0f * 2048.0f;
  char4 o;
  o.x = f2i8(v.x * s); o.y = f2i8(v.y * s); o.z = f2i8(v.z * s); o.w = f2i8(v.w * s);
  *(char4*)(out + i) = o;
}

// WT[j][ch]: ch 0..63 = h-rows (W row 4+ch), 64..67 = x-rows (W row ch-64), 68..95 = 0.
__global__ void build_w(const float* __restrict__ W1, const float* __restrict__ W2,
                        const float* __restrict__ Wih, const float* __restrict__ Whh,
                        const float* __restrict__ D1,
                        u16* __restrict__ WT, u16* __restrict__ WihB,
                        u16* __restrict__ WhhB, u16* __restrict__ D1t){
  int gid = blockIdx.x * 256 + threadIdx.x;
  if (gid < 24576) {
    int j = gid / 96, ch = gid - j * 96;
    float v = 0.0f;
    int rr = (ch < 64) ? (ch + 4) : (ch < 68 ? ch - 64 : -1);
    if (rr >= 0) v = (j < 192) ? W1[(size_t)rr * 192 + j] : W2[(size_t)rr * 64 + (j - 192)];
    WT[gid] = f2bf(v);
  } else if (gid < 40960) {
    int q = gid - 24576; WihB[q] = f2bf(Wih[q]);
  } else if (gid < 57344) {
    int q = gid - 40960; WhhB[q] = f2bf(Whh[q]);
  } else if (gid < 59392) {
    int q = gid - 57344;
    int j = q >> 6, hh = q & 63;
    D1t[q] = f2bf(D1[(size_t)hh * 32 + j]);
  }
}

// PB rows r = b*64+hh (512), init from struc_emb at scale 25.4 (i8)
__global__ void init_pb(const float* __restrict__ struc, int8_t* __restrict__ PB){
  int gid = blockIdx.x * 256 + threadIdx.x;      // 512*4096
  int n = gid & 4095;
  int r = gid >> 12;
  int hh = r & 63;
  PB[(size_t)r * 4096 + n] = f2i8(struc[(size_t)n * 64 + hh] * 25.4f);
}

// Xp[col][n] i8 at scale 25.4, col = t*32 + b*4 + f  (384 rows)
__global__ void pack_xall(const float* __restrict__ X, int8_t* __restrict__ Xp){
  int gid = blockIdx.x * 256 + threadIdx.x;      // 384*4096
  int n = gid & 4095;
  int col = gid >> 12;
  int ts = col >> 5, r = col & 31, b = r >> 2, f = r & 3;
  Xp[(size_t)col * 4096 + n] = f2i8(X[(((size_t)(b * 12 + ts)) * 4096 + n) * 4 + f] * 25.4f);
}

// gact[r=(n*8+b)][j]: j<192 activated gates, 192..255 tanh(conv).
__global__ __launch_bounds__(256)
void enc_update(const u16* __restrict__ gact, const float* __restrict__ struc,
                int8_t* __restrict__ PB, float* __restrict__ zout,
                u16* __restrict__ zbf, int last)
{
  int gid = blockIdx.x * 256 + threadIdx.x;      // 8 * 262144
  int b = gid >> 18;
  int k = gid & 262143;
  int n = k >> 6, hh = k & 63;
  int qi = k + 262144, qo = k + 524288;
  int nf = k  / 192, jf = k  - nf * 192;
  int ni = qi / 192, ji = qi - ni * 192;
  int no = qo / 192, jo = qo - no * 192;
  float fg = bf2f(ntldh(&gact[((size_t)nf * 8 + b) * 256 + jf]));   // NT reads:
  float ig = bf2f(ntldh(&gact[((size_t)ni * 8 + b) * 256 + ji]));   // evict gact
  float og = bf2f(ntldh(&gact[((size_t)no * 8 + b) * 256 + jo]));   // after use
  float tc = bf2f(ntldh(&gact[((size_t)n  * 8 + b) * 256 + 192 + hh]));
  float c  = fg * struc[k] + ig * tc;
  float hv = og * ftanh(c);
  PB[((size_t)(b * 64 + hh)) * 4096 + n] = f2i8(hv * 127.0f);   // |hv|<1
  if (last) {
    zout[(size_t)b * 262144 + k] = hv;
    zbf [(size_t)b * 262144 + k] = f2bf(hv);
  }
}

// ---------------- Fused decoder (unchanged from round 6) ----------------
__global__ __launch_bounds__(256)
void dec_fused(const u16* __restrict__ zbf, const u16* __restrict__ WihB,
               const u16* __restrict__ WhhB,
               const float* __restrict__ bih, const float* __restrict__ bhh,
               const u16* __restrict__ D1t, const float* __restrict__ bd1,
               const float* __restrict__ D2, const float* __restrict__ bd2,
               float* __restrict__ recon)
{
  __shared__ u16 whl[256 * 72];
  __shared__ u16 hl[64 * 72];
  const int t = threadIdx.x;
  const int l = t & 63;
  const int w = t >> 6;
  const int r0 = blockIdx.x * 64;
  const int rA = l & 15;
  const int kg = (l >> 4) * 8;

  for (int c = t; c < 2048; c += 256) {
    int j = c >> 3, k8 = (c & 7) * 8;
    *(uint4*)&whl[j * 72 + k8] = *(const uint4*)&WhhB[j * 64 + k8];
  }

  f4v xg[16];
  {
    s8v a0 = *(const s8v*)&zbf[(size_t)(r0 + w * 16 + rA) * 64 + kg];
    s8v a1 = *(const s8v*)&zbf[(size_t)(r0 + w * 16 + rA) * 64 + 32 + kg];
    #pragma unroll
    for (int nt = 0; nt < 16; ++nt) {
      s8v b0 = *(const s8v*)&WihB[(nt * 16 + rA) * 64 + kg];
      s8v b1 = *(const s8v*)&WihB[(nt * 16 + rA) * 64 + 32 + kg];
      f4v a = (f4v)0.0f;
      a = __builtin_amdgcn_mfma_f32_16x16x32_bf16(a0, b0, a, 0, 0, 0);
      a = __builtin_amdgcn_mfma_f32_16x16x32_bf16(a1, b1, a, 0, 0, 0);
      float bb = bih[nt * 16 + rA] + bhh[nt * 16 + rA];
      #pragma unroll
      for (int r = 0; r < 4; ++r) xg[nt][r] = a[r] + bb;
    }
  }
  s8v d1f[4];
  #pragma unroll
  for (int nt = 0; nt < 2; ++nt)
    #pragma unroll
    for (int kc = 0; kc < 2; ++kc)
      d1f[nt * 2 + kc] = *(const s8v*)&D1t[(nt * 16 + rA) * 64 + kc * 32 + kg];
  const float bd1x = bd1[rA], bd1y = bd1[16 + rA];
  const float d2x = D2[rA], d2y = D2[16 + rA];
  const float bd2v = bd2[0];

  float cst[16];
  #pragma unroll
  for (int q = 0; q < 16; ++q) cst[q] = 0.0f;
  s8v ha0 = (s8v)0, ha1 = (s8v)0;
  __syncthreads();

  for (int s = 0; s < 12; ++s) {
    f4v acc[16];
    #pragma unroll
    for (int nt = 0; nt < 16; ++nt) acc[nt] = xg[nt];
    if (s > 0) {
      #pragma unroll
      for (int nt = 0; nt < 16; ++nt) {
        s8v b0 = *(const s8v*)&whl[(nt * 16 + rA) * 72 + kg];
        s8v b1 = *(const s8v*)&whl[(nt * 16 + rA) * 72 + 32 + kg];
        acc[nt] = __builtin_amdgcn_mfma_f32_16x16x32_bf16(ha0, b0, acc[nt], 0, 0, 0);
        acc[nt] = __builtin_amdgcn_mfma_f32_16x16x32_bf16(ha1, b1, acc[nt], 0, 0, 0);
      }
    }
    #pragma unroll
    for (int q = 0; q < 4; ++q)
      #pragma unroll
      for (int r = 0; r < 4; ++r) {
        float i_ = fsig (acc[q     ][r]);
        float f_ = fsig (acc[q + 4 ][r]);
        float g_ = ftanh(acc[q + 8 ][r]);
        float o_ = fsig (acc[q + 12][r]);
        float cc = f_ * cst[q * 4 + r] + i_ * g_;
        cst[q * 4 + r] = cc;
        float hv = o_ * ftanh(cc);
        hl[(w * 16 + (l >> 4) * 4 + r) * 72 + q * 16 + rA] = f2bf(hv);
      }
    ha0 = *(const s8v*)&hl[(w * 16 + rA) * 72 + kg];
    ha1 = *(const s8v*)&hl[(w * 16 + rA) * 72 + 32 + kg];
    f4v m0 = (f4v)0.0f, m1 = (f4v)0.0f;
    m0 = __builtin_amdgcn_mfma_f32_16x16x32_bf16(ha0, d1f[0], m0, 0, 0, 0);
    m0 = __builtin_amdgcn_mfma_f32_16x16x32_bf16(ha1, d1f[1], m0, 0, 0, 0);
    m1 = __builtin_amdgcn_mfma_f32_16x16x32_bf16(ha0, d1f[2], m1, 0, 0, 0);
    m1 = __builtin_amdgcn_mfma_f32_16x16x32_bf16(ha1, d1f[3], m1, 0, 0, 0);
    f4v p;
    #pragma unroll
    for (int r = 0; r < 4; ++r)
      p[r] = fmaxf(m0[r] + bd1x, 0.0f) * d2x + fmaxf(m1[r] + bd1y, 0.0f) * d2y;
    #pragma unroll
    for (int mask = 1; mask < 16; mask <<= 1)
      #pragma unroll
      for (int r = 0; r < 4; ++r) p[r] += __shfl_xor(p[r], mask);
    if (rA < 4)
      recon[(size_t)(r0 + w * 16 + (l >> 4) * 4 + rA) * 12 + s] = p[rA] + bd2v;
  }
}

extern "C" void kernel_launch(void* const* d_in, const int* in_sizes, int n_in,
                              void* d_out, int out_size, void* d_ws, size_t ws_size,
                              hipStream_t stream)
{
  (void)in_sizes; (void)n_in; (void)out_size; (void)ws_size;
  const float* X     = (const float*)d_in[0];
  const float* adj   = (const float*)d_in[1];
  const float* struc = (const float*)d_in[2];
  const float* W1    = (const float*)d_in[3];
  const float* b1    = (const float*)d_in[4];
  const float* W2    = (const float*)d_in[5];
  const float* b2    = (const float*)d_in[6];
  const float* Wih   = (const float*)d_in[7];
  const float* Whh   = (const float*)d_in[8];
  const float* bih   = (const float*)d_in[9];
  const float* bhh   = (const float*)d_in[10];
  const float* D1    = (const float*)d_in[11];
  const float* bd1   = (const float*)d_in[12];
  const float* D2    = (const float*)d_in[13];
  const float* bd2   = (const float*)d_in[14];

  char* ws = (char*)d_ws;
  size_t off = 0;
  auto alloc = [&](size_t bytes){ void* p = ws + off; off += (bytes + 255) & ~(size_t)255; return p; };
  int8_t* adj_i8 = (int8_t*)alloc(4096ull * 4096);       // 16.75 MB (L2-resident)
  int8_t* PB     = (int8_t*)alloc(512ull * 4096);        // h cols i8 (L2-resident)
  int8_t* Xp     = (int8_t*)alloc(384ull * 4096);        // x cols i8
  u16*   AXb    = (u16*)  alloc(4096ull * 384 * 2);      // adj@X bf16, all steps
  u16*   Cpart  = (u16*)  alloc(4ull * 4096 * 512 * 2);  // split-K slices (streamed)
  u16*   gact   = (u16*)  alloc(32768ull * 256 * 2);     // activated gates (streamed)
  u16*   zbf    = (u16*)  alloc(32768ull * 64 * 2);
  u16*   WT     = (u16*)  alloc(256ull * 96 * 2);
  u16*   WihB   = (u16*)  alloc(256ull * 64 * 2);
  u16*   WhhB   = (u16*)  alloc(256ull * 64 * 2);
  u16*   D1t    = (u16*)  alloc(32ull * 64 * 2);

  float* zout  = (float*)d_out;                   // [B,N,H]
  float* recon = (float*)d_out + 2097152;         // [B*N, S] flat

  // r6-verified dequant scales: adj = q/(127*2048); struc/X = p/25.4; h = p/127
  const float cs5 = (float)(2.0 / 4096.0 * 5.0 / (127.0 * 127.0));  // adj x (struc/X)
  const float cs1 = (float)(2.0 / 4096.0 * 1.0 / (127.0 * 127.0));  // adj x h

  conv_adj_i8<<<16384, 256, 0, stream>>>(adj, adj_i8);
  build_w    <<<  232, 256, 0, stream>>>(W1, W2, Wih, Whh, D1, WT, WihB, WhhB, D1t);
  init_pb    <<< 8192, 256, 0, stream>>>(struc, PB);
  pack_xall  <<< 6144, 256, 0, stream>>>(X, Xp);
  gemm_s1_i8 <<<dim3(32, 3, 4), 256, 0, stream>>>(adj_i8, Xp, Cpart, 384, 1024, cs5);
  reduceN    <<<  768, 256, 0, stream>>>(Cpart, AXb, 4096ull * 384);

  for (int t = 0; t < 12; ++t) {
    gemm_s1_i8<<<dim3(32, 4, 4), 256, 0, stream>>>(adj_i8, PB, Cpart, 512, 1024,
                                                   t == 0 ? cs5 : cs1);
    gemm_s2<<<dim3(512, 4), 256, 0, stream>>>(Cpart, AXb, WT, b1, b2, gact, t);
    enc_update<<<8192, 256, 0, stream>>>(gact, struc, PB, zout, zbf, t == 11);
  }

  dec_fused<<<512, 256, 0, stream>>>(zbf, WihB, WhhB, bih, bhh,
                                     D1t, bd1, D2, bd2, recon);
}

// Round 9
// 593.529 us; speedup vs baseline: 1.7136x; 1.3807x over previous
//
#include <hip/hip_runtime.h>
#include <cstdint>
#include <cstddef>

// B=8, S=12, N=4096, F=4, H=64
// r9 = r6 base (771us) with:
//  - s1: BK=128, single-barrier double-buffered global_load_lds (prefetch next
//    tile across the barrier; 8 iters/dispatch, 1 barrier/iter) — attacks the
//    measured ~21us per-dispatch constant (dur = bytes/1.75TBps + C).
//  - s2 epilogue stores gates PRE-PERMUTED to G[role][b][k] (flat-split map is
//    a bijection); enc_update becomes coalesced u16x8 reads + LDS transpose so
//    PB writes are 8B-contiguous (was 1B/thread @ stride 4096).
//  - all r7/r8 non-temporal hints reverted.

typedef unsigned short u16;
typedef short s8v __attribute__((ext_vector_type(8)));     // 8 x bf16 bits
typedef unsigned short h8v __attribute__((ext_vector_type(8))); // 8 x u16
typedef float f4v __attribute__((ext_vector_type(4)));     // fp32 MFMA acc
typedef int   i4v __attribute__((ext_vector_type(4)));     // i8 MFMA operands/acc

__device__ __forceinline__ u16 f2bf(float x){
  union { float f; uint32_t u; } v; v.f = x;
  uint32_t r = v.u + 0x7FFFu + ((v.u >> 16) & 1u);   // RNE
  return (u16)(r >> 16);
}
__device__ __forceinline__ float bf2f(u16 x){
  union { uint32_t u; float f; } v; v.u = ((uint32_t)x) << 16; return v.f;
}
__device__ __forceinline__ float frcp(float x){ return __builtin_amdgcn_rcpf(x); }
__device__ __forceinline__ float fsig(float x){ return frcp(1.0f + __expf(-x)); }
__device__ __forceinline__ float ftanh(float x){ return 1.0f - 2.0f * frcp(1.0f + __expf(2.0f * x)); }
__device__ __forceinline__ int8_t f2i8(float x){
  int v = (int)rintf(x);
  v = v > 127 ? 127 : (v < -127 ? -127 : v);
  return (int8_t)v;
}

typedef const __attribute__((address_space(1))) unsigned int* gp_t;
typedef __attribute__((address_space(3))) unsigned int* lp_t;
__device__ __forceinline__ void glds16(const void* g, void* l){
  __builtin_amdgcn_global_load_lds((gp_t)g, (lp_t)l, 16, 0, 0);
}

// ---------------- Stage-1 INT8: 128x128 tile, BK=128, dbuf, split-K ----------------
// A [4096][4096] i8, Bt [Ncols][4096] i8, Cpart[z][4096][Ncols] bf16 (scaled).
// LDS: 2 bufs x (As 16KB + Bs 16KB) = 64KB. Physical chunk (row, cp) holds
// global 16B-chunk cp ^ (row&7); frag read col q' = (sub*4 + (l>>4)) ^ (l&7)
// -> 8 distinct bank-cols x 2 rows = 2-way (free).
__global__ __launch_bounds__(256)
void gemm_s1_i8(const int8_t* __restrict__ A, const int8_t* __restrict__ Bt,
                u16* __restrict__ Cpart, int Ncols, int ksl, float cscale)
{
  __shared__ int8_t As[2 * 128 * 128];
  __shared__ int8_t Bs[2 * 128 * 128];
  const int t  = threadIdx.x;
  const int l  = t & 63;
  const int w  = t >> 6;
  const int wm = (w >> 1) * 64;
  const int wc = (w & 1) * 64;
  const int mb = blockIdx.x * 128;
  const int nb = blockIdx.y * 128;
  const int k0 = blockIdx.z * ksl;

  i4v acc[4][4];
  #pragma unroll
  for (int i = 0; i < 4; ++i)
    #pragma unroll
    for (int j = 0; j < 4; ++j) acc[i][j] = (i4v)0;

  // staging: thread t loads chunks c = t + 256*j (j=0..3) per matrix:
  // row = c>>3 = (t>>3) + 32*j, cp = c&7 = t&7; global chunk g = cp ^ (row&7)
  const int srow = t >> 3;
  const int gsw  = ((t & 7) ^ (srow & 7)) * 16;   // (row+32j)&7 == row&7
  const int8_t* ab = A  + (size_t)(mb + srow) * 4096 + k0 + gsw;
  const int8_t* bb = Bt + (size_t)(nb + srow) * 4096 + k0 + gsw;

  const int rA = l & 15;
  const int lsw = l & 7;

  // prefetch tile 0 into buf 0
  #pragma unroll
  for (int j = 0; j < 4; ++j) {
    glds16(ab + (size_t)(32 * j) * 4096, As + j * 4096 + t * 16);
    glds16(bb + (size_t)(32 * j) * 4096, Bs + j * 4096 + t * 16);
  }

  for (int kk = 0; kk < ksl; kk += 128) {
    const int cur = (kk >> 7) & 1;
    __syncthreads();   // buf[cur] ready; buf[cur^1] free (reads done last iter)
    if (kk + 128 < ksl) {
      const int nxt = cur ^ 1;
      #pragma unroll
      for (int j = 0; j < 4; ++j) {
        glds16(ab + (size_t)(32 * j) * 4096 + kk + 128, As + nxt * 16384 + j * 4096 + t * 16);
        glds16(bb + (size_t)(32 * j) * 4096 + kk + 128, Bs + nxt * 16384 + j * 4096 + t * 16);
      }
    }
    const int bofs = cur * 16384;
    #pragma unroll
    for (int sub = 0; sub < 2; ++sub) {
      const int kpos = ((sub * 4 + (l >> 4)) ^ lsw) * 16;
      i4v af[4], bf[4];
      #pragma unroll
      for (int mt = 0; mt < 4; ++mt)
        af[mt] = *(const i4v*)&As[bofs + (wm + mt * 16 + rA) * 128 + kpos];
      #pragma unroll
      for (int nt = 0; nt < 4; ++nt)
        bf[nt] = *(const i4v*)&Bs[bofs + (wc + nt * 16 + rA) * 128 + kpos];
      #pragma unroll
      for (int mt = 0; mt < 4; ++mt)
        #pragma unroll
        for (int nt = 0; nt < 4; ++nt)
          acc[mt][nt] = __builtin_amdgcn_mfma_i32_16x16x64_i8(af[mt], bf[nt], acc[mt][nt], 0, 0, 0);
    }
  }

  u16* Cs = Cpart + (size_t)blockIdx.z * 4096 * Ncols;
  const int colo = l & 15;
  const int rowo = (l >> 4) * 4;
  #pragma unroll
  for (int mt = 0; mt < 4; ++mt)
    #pragma unroll
    for (int nt = 0; nt < 4; ++nt)
      #pragma unroll
      for (int r = 0; r < 4; ++r) {
        int gr = mb + wm + mt * 16 + rowo + r;
        int gc = nb + wc + nt * 16 + colo;
        Cs[(size_t)gr * Ncols + gc] = f2bf((float)acc[mt][nt][r] * cscale);
      }
}

// O[i] = sum_{z<4} P[z*SL + i]  (bf16) — used once for the AX hoist
__global__ __launch_bounds__(256)
void reduceN(const u16* __restrict__ P, u16* __restrict__ O, size_t SL)
{
  size_t i = ((size_t)blockIdx.x * 256 + threadIdx.x) * 8;
  if (i >= SL) return;
  float s[8] = {0,0,0,0,0,0,0,0};
  #pragma unroll
  for (int z = 0; z < 4; ++z) {
    uint4 v = *(const uint4*)(P + z * SL + i);
    uint32_t wd[4] = {v.x, v.y, v.z, v.w};
    #pragma unroll
    for (int q = 0; q < 4; ++q) {
      union { uint32_t u; float f; } lo, hi;
      lo.u = wd[q] << 16; hi.u = wd[q] & 0xFFFF0000u;
      s[2*q] += lo.f; s[2*q+1] += hi.f;
    }
  }
  uint4 o; uint32_t* ow = (uint32_t*)&o;
  #pragma unroll
  for (int q = 0; q < 4; ++q)
    ow[q] = (uint32_t)f2bf(s[2*q]) | ((uint32_t)f2bf(s[2*q+1]) << 16);
  *(uint4*)(O + i) = o;
}

// ---------- Stage-2 fused: (sum 4 AH slices | AX x-cols | pad) @ WT^T, then
// bias + activation, stores PERMUTED: G[role][b][k], role 0/1/2 = f/i/o
// (p = n'*192+gc; role = p>>18; k = p & (NH-1)), role 3 = tanh(conv) at
// k = n'*64 + (gc-192). 16-lane store runs never straddle a role boundary.
__global__ __launch_bounds__(256)
void gemm_s2(const u16* __restrict__ AH, const u16* __restrict__ AXb,
             const u16* __restrict__ WT, const float* __restrict__ b1v,
             const float* __restrict__ b2v, u16* __restrict__ G, int tstep)
{
  __shared__ u16 As[64*104];
  __shared__ u16 Bs[64*104];
  const int t = threadIdx.x;
  const int l = t & 63, w = t >> 6;
  const int wm = (w >> 1) * 32, wc = (w & 1) * 32;
  const int mb = blockIdx.x * 64, nb = blockIdx.y * 64;
  const size_t SL = 32768ull * 64;

  #pragma unroll
  for (int pass = 0; pass < 2; ++pass) {
    int idx = t + pass * 256;
    int row = idx >> 3, oct = idx & 7;
    size_t base = (size_t)(mb + row) * 64 + oct * 8;
    float s[8] = {0,0,0,0,0,0,0,0};
    #pragma unroll
    for (int z = 0; z < 4; ++z) {
      uint4 v = *(const uint4*)(AH + z * SL + base);
      uint32_t wd[4] = {v.x, v.y, v.z, v.w};
      #pragma unroll
      for (int q = 0; q < 4; ++q) {
        union { uint32_t u; float f; } lo, hi;
        lo.u = wd[q] << 16; hi.u = wd[q] & 0xFFFF0000u;
        s[2*q] += lo.f; s[2*q+1] += hi.f;
      }
    }
    uint4 o; uint32_t* ow = (uint32_t*)&o;
    #pragma unroll
    for (int q = 0; q < 4; ++q)
      ow[q] = (uint32_t)f2bf(s[2*q]) | ((uint32_t)f2bf(s[2*q+1]) << 16);
    *(uint4*)&As[row * 104 + oct * 8] = o;
  }
  {
    int row = t >> 2, q = t & 3;
    uint4 o = {0, 0, 0, 0};
    if (q == 0) {
      int r = mb + row, n = r >> 3, b = r & 7;
      const uint32_t* src = (const uint32_t*)(AXb + (size_t)n * 384 + tstep * 32 + b * 4);
      o.x = src[0]; o.y = src[1];
    }
    *(uint4*)&As[row * 104 + 64 + q * 8] = o;
  }
  #pragma unroll
  for (int pass = 0; pass < 3; ++pass) {
    int idx = t + pass * 256;
    if (idx < 768) {
      int row = idx / 12, seg = idx - row * 12;
      *(uint4*)&Bs[row * 104 + seg * 8] = *(const uint4*)(WT + (size_t)(nb + row) * 96 + seg * 8);
    }
  }
  __syncthreads();

  f4v acc[2][2];
  #pragma unroll
  for (int i = 0; i < 2; ++i)
    #pragma unroll
    for (int j = 0; j < 2; ++j) acc[i][j] = (f4v)0.0f;
  const int rA = l & 15, kg = (l >> 4) * 8;
  #pragma unroll
  for (int kc = 0; kc < 3; ++kc) {
    s8v af[2], bf[2];
    #pragma unroll
    for (int mt = 0; mt < 2; ++mt)
      af[mt] = *(const s8v*)&As[(wm + mt * 16 + rA) * 104 + kc * 32 + kg];
    #pragma unroll
    for (int nt = 0; nt < 2; ++nt)
      bf[nt] = *(const s8v*)&Bs[(wc + nt * 16 + rA) * 104 + kc * 32 + kg];
    #pragma unroll
    for (int mt = 0; mt < 2; ++mt)
      #pragma unroll
      for (int nt = 0; nt < 2; ++nt)
        acc[mt][nt] = __builtin_amdgcn_mfma_f32_16x16x32_bf16(af[mt], bf[nt], acc[mt][nt], 0, 0, 0);
  }

  const int colo = l & 15, rowo = (l >> 4) * 4;
  #pragma unroll
  for (int mt = 0; mt < 2; ++mt)
    #pragma unroll
    for (int nt = 0; nt < 2; ++nt) {
      int gc = nb + wc + nt * 16 + colo;
      float bb = (gc < 192) ? b1v[gc] : b2v[gc - 192];
      #pragma unroll
      for (int r = 0; r < 4; ++r) {
        int gr = mb + wm + mt * 16 + rowo + r;
        int np = gr >> 3, b = gr & 7;
        float v = acc[mt][nt][r] + bb;
        size_t addr;
        u16 val;
        if (gc < 192) {
          int p = np * 192 + gc;
          int role = p >> 18;
          int k = p & 262143;
          addr = ((size_t)(role * 8 + b) << 18) + k;
          val = f2bf(fsig(v));
        } else {
          int k = np * 64 + (gc - 192);
          addr = ((size_t)(24 + b) << 18) + k;
          val = f2bf(ftanh(v));
        }
        G[addr] = val;
      }
    }
}

// adj fp32 -> i8 fixed-point: round(adj * 127*2048), adj in [0, 2/4096)
__global__ void conv_adj_i8(const float* __restrict__ adj, int8_t* __restrict__ out){
  size_t i = ((size_t)blockIdx.x * 256 + threadIdx.x) * 4;
  float4 v = *(const float4*)(adj + i);
  const float s = 127.0f * 2048.0f;
  char4 o;
  o.x = f2i8(v.x * s); o.y = f2i8(v.y * s); o.z = f2i8(v.z * s); o.w = f2i8(v.w * s);
  *(char4*)(out + i) = o;
}

// WT[j][ch]: ch 0..63 = h-rows (W row 4+ch), 64..67 = x-rows (W row ch-64), 68..95 = 0.
__global__ void build_w(const float* __restrict__ W1, const float* __restrict__ W2,
                        const float* __restrict__ Wih, const float* __restrict__ Whh,
                        const float* __restrict__ D1,
                        u16* __restrict__ WT, u16* __restrict__ WihB,
                        u16* __restrict__ WhhB, u16* __restrict__ D1t){
  int gid = blockIdx.x * 256 + threadIdx.x;
  if (gid < 24576) {
    int j = gid / 96, ch = gid - j * 96;
    float v = 0.0f;
    int rr = (ch < 64) ? (ch + 4) : (ch < 68 ? ch - 64 : -1);
    if (rr >= 0) v = (j < 192) ? W1[(size_t)rr * 192 + j] : W2[(size_t)rr * 64 + (j - 192)];
    WT[gid] = f2bf(v);
  } else if (gid < 40960) {
    int q = gid - 24576; WihB[q] = f2bf(Wih[q]);
  } else if (gid < 57344) {
    int q = gid - 40960; WhhB[q] = f2bf(Whh[q]);
  } else if (gid < 59392) {
    int q = gid - 57344;
    int j = q >> 6, hh = q & 63;
    D1t[q] = f2bf(D1[(size_t)hh * 32 + j]);
  }
}

// PB rows r = b*64+hh (512), init from struc_emb at scale 25.4 (i8)
__global__ void init_pb(const float* __restrict__ struc, int8_t* __restrict__ PB){
  int gid = blockIdx.x * 256 + threadIdx.x;      // 512*4096
  int n = gid & 4095;
  int r = gid >> 12;
  int hh = r & 63;
  PB[(size_t)r * 4096 + n] = f2i8(struc[(size_t)n * 64 + hh] * 25.4f);
}

// Xp[col][n] i8 at scale 25.4, col = t*32 + b*4 + f  (384 rows)
__global__ void pack_xall(const float* __restrict__ X, int8_t* __restrict__ Xp){
  int gid = blockIdx.x * 256 + threadIdx.x;      // 384*4096
  int n = gid & 4095;
  int col = gid >> 12;
  int ts = col >> 5, r = col & 31, b = r >> 2, f = r & 3;
  Xp[(size_t)col * 4096 + n] = f2i8(X[(((size_t)(b * 12 + ts)) * 4096 + n) * 4 + f] * 25.4f);
}

// enc_update v2: fully-coalesced G reads (u16x8) + LDS transpose for PB writes.
// Block = (b, 32-node chunk): grid 1024 x 256; thread t handles k8 = n0*64 + t*8
// (one n, 8 consecutive hh).
__global__ __launch_bounds__(256)
void enc_update(const u16* __restrict__ G, const float* __restrict__ struc,
                int8_t* __restrict__ PB, float* __restrict__ zout,
                u16* __restrict__ zbf, int last)
{
  __shared__ uint8_t hx[64 * 40];   // [hh][n_local], stride 40 (8B-aligned rows)
  const int t = threadIdx.x;
  const int b = blockIdx.x >> 7;
  const int n0 = (blockIdx.x & 127) * 32;
  const int k8 = n0 * 64 + t * 8;
  const int nloc = t >> 3;
  const int hh0 = (t & 7) * 8;

  h8v f8 = *(const h8v*)&G[((size_t)(     b) << 18) + k8];
  h8v i8_ = *(const h8v*)&G[((size_t)( 8 + b) << 18) + k8];
  h8v o8 = *(const h8v*)&G[((size_t)(16 + b) << 18) + k8];
  h8v c8 = *(const h8v*)&G[((size_t)(24 + b) << 18) + k8];
  float4 s0 = *(const float4*)&struc[k8];
  float4 s1 = *(const float4*)&struc[k8 + 4];
  float sv[8] = {s0.x, s0.y, s0.z, s0.w, s1.x, s1.y, s1.z, s1.w};

  float hv[8];
  #pragma unroll
  for (int j = 0; j < 8; ++j) {
    float c = bf2f(f8[j]) * sv[j] + bf2f(i8_[j]) * bf2f(c8[j]);
    hv[j] = bf2f(o8[j]) * ftanh(c);
    hx[(hh0 + j) * 40 + nloc] = (uint8_t)f2i8(hv[j] * 127.0f);
  }
  if (last) {
    float4 z0 = {hv[0], hv[1], hv[2], hv[3]};
    float4 z1 = {hv[4], hv[5], hv[6], hv[7]};
    *(float4*)&zout[((size_t)b << 18) + k8] = z0;
    *(float4*)&zout[((size_t)b << 18) + k8 + 4] = z1;
    h8v zb;
    #pragma unroll
    for (int j = 0; j < 8; ++j) zb[j] = f2bf(hv[j]);
    *(h8v*)&zbf[((size_t)b << 18) + k8] = zb;
  }
  __syncthreads();
  // write-out: thread t -> PB row hh = t>>2, 8 bytes at n0 + (t&3)*8
  {
    int row = t >> 2, seg = t & 3;
    uint2 v = *(const uint2*)&hx[row * 40 + seg * 8];
    *(uint2*)&PB[(size_t)(b * 64 + row) * 4096 + n0 + seg * 8] = v;
  }
}

// ---------------- Fused decoder (unchanged from round 6) ----------------
__global__ __launch_bounds__(256)
void dec_fused(const u16* __restrict__ zbf, const u16* __restrict__ WihB,
               const u16* __restrict__ WhhB,
               const float* __restrict__ bih, const float* __restrict__ bhh,
               const u16* __restrict__ D1t, const float* __restrict__ bd1,
               const float* __restrict__ D2, const float* __restrict__ bd2,
               float* __restrict__ recon)
{
  __shared__ u16 whl[256 * 72];
  __shared__ u16 hl[64 * 72];
  const int t = threadIdx.x;
  const int l = t & 63;
  const int w = t >> 6;
  const int r0 = blockIdx.x * 64;
  const int rA = l & 15;
  const int kg = (l >> 4) * 8;

  for (int c = t; c < 2048; c += 256) {
    int j = c >> 3, k8 = (c & 7) * 8;
    *(uint4*)&whl[j * 72 + k8] = *(const uint4*)&WhhB[j * 64 + k8];
  }

  f4v xg[16];
  {
    s8v a0 = *(const s8v*)&zbf[(size_t)(r0 + w * 16 + rA) * 64 + kg];
    s8v a1 = *(const s8v*)&zbf[(size_t)(r0 + w * 16 + rA) * 64 + 32 + kg];
    #pragma unroll
    for (int nt = 0; nt < 16; ++nt) {
      s8v b0 = *(const s8v*)&WihB[(nt * 16 + rA) * 64 + kg];
      s8v b1 = *(const s8v*)&WihB[(nt * 16 + rA) * 64 + 32 + kg];
      f4v a = (f4v)0.0f;
      a = __builtin_amdgcn_mfma_f32_16x16x32_bf16(a0, b0, a, 0, 0, 0);
      a = __builtin_amdgcn_mfma_f32_16x16x32_bf16(a1, b1, a, 0, 0, 0);
      float bb = bih[nt * 16 + rA] + bhh[nt * 16 + rA];
      #pragma unroll
      for (int r = 0; r < 4; ++r) xg[nt][r] = a[r] + bb;
    }
  }
  s8v d1f[4];
  #pragma unroll
  for (int nt = 0; nt < 2; ++nt)
    #pragma unroll
    for (int kc = 0; kc < 2; ++kc)
      d1f[nt * 2 + kc] = *(const s8v*)&D1t[(nt * 16 + rA) * 64 + kc * 32 + kg];
  const float bd1x = bd1[rA], bd1y = bd1[16 + rA];
  const float d2x = D2[rA], d2y = D2[16 + rA];
  const float bd2v = bd2[0];

  float cst[16];
  #pragma unroll
  for (int q = 0; q < 16; ++q) cst[q] = 0.0f;
  s8v ha0 = (s8v)0, ha1 = (s8v)0;
  __syncthreads();

  for (int s = 0; s < 12; ++s) {
    f4v acc[16];
    #pragma unroll
    for (int nt = 0; nt < 16; ++nt) acc[nt] = xg[nt];
    if (s > 0) {
      #pragma unroll
      for (int nt = 0; nt < 16; ++nt) {
        s8v b0 = *(const s8v*)&whl[(nt * 16 + rA) * 72 + kg];
        s8v b1 = *(const s8v*)&whl[(nt * 16 + rA) * 72 + 32 + kg];
        acc[nt] = __builtin_amdgcn_mfma_f32_16x16x32_bf16(ha0, b0, acc[nt], 0, 0, 0);
        acc[nt] = __builtin_amdgcn_mfma_f32_16x16x32_bf16(ha1, b1, acc[nt], 0, 0, 0);
      }
    }
    #pragma unroll
    for (int q = 0; q < 4; ++q)
      #pragma unroll
      for (int r = 0; r < 4; ++r) {
        float i_ = fsig (acc[q     ][r]);
        float f_ = fsig (acc[q + 4 ][r]);
        float g_ = ftanh(acc[q + 8 ][r]);
        float o_ = fsig (acc[q + 12][r]);
        float cc = f_ * cst[q * 4 + r] + i_ * g_;
        cst[q * 4 + r] = cc;
        float hv = o_ * ftanh(cc);
        hl[(w * 16 + (l >> 4) * 4 + r) * 72 + q * 16 + rA] = f2bf(hv);
      }
    ha0 = *(const s8v*)&hl[(w * 16 + rA) * 72 + kg];
    ha1 = *(const s8v*)&hl[(w * 16 + rA) * 72 + 32 + kg];
    f4v m0 = (f4v)0.0f, m1 = (f4v)0.0f;
    m0 = __builtin_amdgcn_mfma_f32_16x16x32_bf16(ha0, d1f[0], m0, 0, 0, 0);
    m0 = __builtin_amdgcn_mfma_f32_16x16x32_bf16(ha1, d1f[1], m0, 0, 0, 0);
    m1 = __builtin_amdgcn_mfma_f32_16x16x32_bf16(ha0, d1f[2], m1, 0, 0, 0);
    m1 = __builtin_amdgcn_mfma_f32_16x16x32_bf16(ha1, d1f[3], m1, 0, 0, 0);
    f4v p;
    #pragma unroll
    for (int r = 0; r < 4; ++r)
      p[r] = fmaxf(m0[r] + bd1x, 0.0f) * d2x + fmaxf(m1[r] + bd1y, 0.0f) * d2y;
    #pragma unroll
    for (int mask = 1; mask < 16; mask <<= 1)
      #pragma unroll
      for (int r = 0; r < 4; ++r) p[r] += __shfl_xor(p[r], mask);
    if (rA < 4)
      recon[(size_t)(r0 + w * 16 + (l >> 4) * 4 + rA) * 12 + s] = p[rA] + bd2v;
  }
}

extern "C" void kernel_launch(void* const* d_in, const int* in_sizes, int n_in,
                              void* d_out, int out_size, void* d_ws, size_t ws_size,
                              hipStream_t stream)
{
  (void)in_sizes; (void)n_in; (void)out_size; (void)ws_size;
  const float* X     = (const float*)d_in[0];
  const float* adj   = (const float*)d_in[1];
  const float* struc = (const float*)d_in[2];
  const float* W1    = (const float*)d_in[3];
  const float* b1    = (const float*)d_in[4];
  const float* W2    = (const float*)d_in[5];
  const float* b2    = (const float*)d_in[6];
  const float* Wih   = (const float*)d_in[7];
  const float* Whh   = (const float*)d_in[8];
  const float* bih   = (const float*)d_in[9];
  const float* bhh   = (const float*)d_in[10];
  const float* D1    = (const float*)d_in[11];
  const float* bd1   = (const float*)d_in[12];
  const float* D2    = (const float*)d_in[13];
  const float* bd2   = (const float*)d_in[14];

  char* ws = (char*)d_ws;
  size_t off = 0;
  auto alloc = [&](size_t bytes){ void* p = ws + off; off += (bytes + 255) & ~(size_t)255; return p; };
  int8_t* adj_i8 = (int8_t*)alloc(4096ull * 4096);       // 16.75 MB
  int8_t* PB     = (int8_t*)alloc(512ull * 4096);        // h cols i8 [b*64+hh][n]
  int8_t* Xp     = (int8_t*)alloc(384ull * 4096);        // x cols i8 (scale 25.4)
  u16*   AXb    = (u16*)  alloc(4096ull * 384 * 2);      // adj@X bf16, all steps
  u16*   Cpart  = (u16*)  alloc(4ull * 4096 * 512 * 2);  // split-K slices bf16
  u16*   G      = (u16*)  alloc(4ull * 8 * 262144 * 2);  // permuted gates [role][b][k]
  u16*   zbf    = (u16*)  alloc(32768ull * 64 * 2);
  u16*   WT     = (u16*)  alloc(256ull * 96 * 2);
  u16*   WihB   = (u16*)  alloc(256ull * 64 * 2);
  u16*   WhhB   = (u16*)  alloc(256ull * 64 * 2);
  u16*   D1t    = (u16*)  alloc(32ull * 64 * 2);

  float* zout  = (float*)d_out;                   // [B,N,H]
  float* recon = (float*)d_out + 2097152;         // [B*N, S] flat

  // dequant scales: adj lsb = 1/(127*2048); struc/X lsb = 1/25.4; h lsb = 1/127
  const float cs5 = (float)(2.0 / 4096.0 * 5.0 / (127.0 * 127.0));  // adj x (struc/X)
  const float cs1 = (float)(2.0 / 4096.0 * 1.0 / (127.0 * 127.0));  // adj x h

  conv_adj_i8<<<16384, 256, 0, stream>>>(adj, adj_i8);
  build_w    <<<  232, 256, 0, stream>>>(W1, W2, Wih, Whh, D1, WT, WihB, WhhB, D1t);
  init_pb    <<< 8192, 256, 0, stream>>>(struc, PB);
  pack_xall  <<< 6144, 256, 0, stream>>>(X, Xp);
  gemm_s1_i8 <<<dim3(32, 3, 4), 256, 0, stream>>>(adj_i8, Xp, Cpart, 384, 1024, cs5);
  reduceN    <<<  768, 256, 0, stream>>>(Cpart, AXb, 4096ull * 384);

  for (int t = 0; t < 12; ++t) {
    gemm_s1_i8<<<dim3(32, 4, 4), 256, 0, stream>>>(adj_i8, PB, Cpart, 512, 1024,
                                                   t == 0 ? cs5 : cs1);
    gemm_s2<<<dim3(512, 4), 256, 0, stream>>>(Cpart, AXb, WT, b1, b2, G, t);
    enc_update<<<1024, 256, 0, stream>>>(G, struc, PB, zout, zbf, t == 11);
  }

  dec_fused<<<512, 256, 0, stream>>>(zbf, WihB, WhhB, bih, bhh,
                                     D1t, bd1, D2, bd2, recon);
}